// Round 1
// baseline (6523.297 us; speedup 1.0000x reference)
//
#include <hip/hip_runtime.h>
#include <hip/hip_bf16.h>

#define N_NODES 131072
#define N_EDGES 1048576
#define HID 128
#define NB 512
#define PPG 32

// ---------------------------------------------------------------------------
// init_forward edge pass: for etype==0 edges, agg0[dst] += emb_table[gid[src]]*norm
// and deg[dst] += 1.  32 lanes per edge, float4 per lane.
// ---------------------------------------------------------------------------
__global__ void edge_init_kernel(const int* __restrict__ src, const int* __restrict__ dst,
                                 const int* __restrict__ etype, const float* __restrict__ norm,
                                 const int* __restrict__ global_id,
                                 const float* __restrict__ emb_table,
                                 float* __restrict__ agg0, float* __restrict__ deg) {
    long long tid = (long long)blockIdx.x * blockDim.x + threadIdx.x;
    int e = (int)(tid >> 5);
    int c = (int)(tid & 31);
    if (e >= N_EDGES) return;
    if (etype[e] != 0) return;
    int s = src[e], d = dst[e];
    float nm = norm[e];
    if (c == 0) unsafeAtomicAdd(deg + d, 1.0f);
    int gid = global_id[s];
    float4 v = ((const float4*)(emb_table + (size_t)gid * HID))[c];
    float* out = agg0 + (size_t)d * HID + (size_t)c * 4;
    unsafeAtomicAdd(out + 0, v.x * nm);
    unsafeAtomicAdd(out + 1, v.y * nm);
    unsafeAtomicAdd(out + 2, v.z * nm);
    unsafeAtomicAdd(out + 3, v.w * nm);
}

// ---------------------------------------------------------------------------
// input projection: h[n] = concat(emb', spo, access, pre_access) @ W_t + b_t
// emb'[n] = (is_ne && deg>0) ? agg0[n] : emb_table[global_id[n]]
// one 128-thread block per node; node row staged in LDS.
// ---------------------------------------------------------------------------
__global__ void proj_kernel(const float* __restrict__ emb_table, const int* __restrict__ global_id,
                            const int* __restrict__ spo, const int* __restrict__ access,
                            const int* __restrict__ pre_access,
                            const float* __restrict__ agg0, const float* __restrict__ deg,
                            const float* __restrict__ W_t, const float* __restrict__ b_t,
                            float* __restrict__ h) {
    int n = blockIdx.x;
    int j = threadIdx.x;
    __shared__ float x[HID];
    int s0 = spo[n * 3 + 0], s1 = spo[n * 3 + 1], s2 = spo[n * 3 + 2];
    bool use_agg = ((s0 + s2) > 0) && (deg[n] > 0.0f);
    float e;
    if (use_agg) e = agg0[(size_t)n * HID + j];
    else         e = emb_table[(size_t)global_id[n] * HID + j];
    x[j] = e;
    __syncthreads();
    float acc = b_t[j];
#pragma unroll 8
    for (int i = 0; i < HID; ++i) acc += x[i] * W_t[i * HID + j];
    float f0 = (float)s0, f1 = (float)s1, f2 = (float)s2;
    float fa = (float)access[n], fp = (float)pre_access[n];
    acc += f0 * W_t[128 * HID + j] + f1 * W_t[129 * HID + j] + f2 * W_t[130 * HID + j]
         + fa * W_t[131 * HID + j] + fp * W_t[132 * HID + j];
    h[(size_t)n * HID + j] = acc;
}

// ---------------------------------------------------------------------------
// xt = h @ W_r[l,t]  (one 128-thread block per node)
// ---------------------------------------------------------------------------
__global__ void xt_kernel(const float* __restrict__ h, const float* __restrict__ Wr,
                          float* __restrict__ xt) {
    int n = blockIdx.x, j = threadIdx.x;
    __shared__ float x[HID];
    x[j] = h[(size_t)n * HID + j];
    __syncthreads();
    float acc = 0.f;
#pragma unroll 8
    for (int i = 0; i < HID; ++i) acc += x[i] * Wr[i * HID + j];
    xt[(size_t)n * HID + j] = acc;
}

// ---------------------------------------------------------------------------
// RGCN edge pass for one type: agg[dst] += xt[src] * norm  (etype==t edges)
// ---------------------------------------------------------------------------
__global__ void edge_rgcn_kernel(const int* __restrict__ src, const int* __restrict__ dst,
                                 const int* __restrict__ etype, const float* __restrict__ norm,
                                 const float* __restrict__ xt, float* __restrict__ agg, int t) {
    long long tid = (long long)blockIdx.x * blockDim.x + threadIdx.x;
    int e = (int)(tid >> 5), c = (int)(tid & 31);
    if (e >= N_EDGES) return;
    if (etype[e] != t) return;
    int s = src[e], d = dst[e];
    float nm = norm[e];
    float4 v = ((const float4*)(xt + (size_t)s * HID))[c];
    float* out = agg + (size_t)d * HID + (size_t)c * 4;
    unsafeAtomicAdd(out + 0, v.x * nm);
    unsafeAtomicAdd(out + 1, v.y * nm);
    unsafeAtomicAdd(out + 2, v.z * nm);
    unsafeAtomicAdd(out + 3, v.w * nm);
}

// ---------------------------------------------------------------------------
// h = relu(agg + b_r[l]) (+ h if residual)   -- elementwise, in place on h
// ---------------------------------------------------------------------------
__global__ void update_kernel(float* __restrict__ h, const float* __restrict__ agg,
                              const float* __restrict__ b_r, int residual) {
    int idx = blockIdx.x * blockDim.x + threadIdx.x; // over N*HID
    int j = idx & (HID - 1);
    float v = agg[idx] + b_r[j];
    v = v > 0.f ? v : 0.f;
    if (residual) v += h[idx];
    h[idx] = v;
}

// ---------------------------------------------------------------------------
// predict: per graph (block): gather hp[32][128], pool mean, v = Wb @ pool,
// s[p] = <hp[p], v> + bb, log_softmax over 32, write out.
// ---------------------------------------------------------------------------
__global__ void predict_kernel(const float* __restrict__ h, const int* __restrict__ pred_idx,
                               const float* __restrict__ Wb, const float* __restrict__ bbp,
                               float* __restrict__ out) {
    int b = blockIdx.x;
    int tid = threadIdx.x; // 256
    __shared__ float hp[PPG * HID];
    __shared__ float pool[HID];
    __shared__ float vv[HID];
    __shared__ float sc[PPG];
    __shared__ float lse;
    for (int k = tid; k < PPG * HID; k += 256) {
        int p = k >> 7, j = k & 127;
        int node = pred_idx[b * PPG + p];
        hp[k] = h[(size_t)node * HID + j];
    }
    __syncthreads();
    if (tid < HID) {
        float s = 0.f;
        for (int p = 0; p < PPG; ++p) s += hp[p * HID + tid];
        pool[tid] = s * (1.0f / PPG);
    }
    __syncthreads();
    if (tid < HID) {
        float s = 0.f;
        for (int k = 0; k < HID; ++k) s += Wb[tid * HID + k] * pool[k];
        vv[tid] = s;
    }
    __syncthreads();
    if (tid < PPG) {
        float s = bbp[0];
        for (int j = 0; j < HID; ++j) s += hp[tid * HID + j] * vv[j];
        sc[tid] = s;
    }
    __syncthreads();
    if (tid == 0) {
        float m = -INFINITY;
        for (int p = 0; p < PPG; ++p) m = fmaxf(m, sc[p]);
        float se = 0.f;
        for (int p = 0; p < PPG; ++p) se += expf(sc[p] - m);
        lse = m + logf(se);
    }
    __syncthreads();
    if (tid < PPG) out[b * PPG + tid] = sc[tid] - lse;
}

extern "C" void kernel_launch(void* const* d_in, const int* in_sizes, int n_in,
                              void* d_out, int out_size, void* d_ws, size_t ws_size,
                              hipStream_t stream) {
    const float* emb_table  = (const float*)d_in[0];
    const float* W_t        = (const float*)d_in[1];
    const float* b_t        = (const float*)d_in[2];
    const float* W_r        = (const float*)d_in[3];
    const float* b_r        = (const float*)d_in[4];
    const float* Wb         = (const float*)d_in[5];
    const float* bb         = (const float*)d_in[6];
    const float* norm       = (const float*)d_in[7];
    const int*   global_id  = (const int*)d_in[8];
    const int*   spo        = (const int*)d_in[9];
    const int*   access     = (const int*)d_in[10];
    const int*   pre_access = (const int*)d_in[11];
    const int*   src        = (const int*)d_in[12];
    const int*   dst        = (const int*)d_in[13];
    const int*   etype      = (const int*)d_in[14];
    const int*   pred_idx   = (const int*)d_in[15];
    float* out = (float*)d_out;

    char* ws = (char*)d_ws;
    size_t NH = (size_t)N_NODES * HID * sizeof(float);   // 64 MiB
    float* buf1 = (float*)(ws);              // agg0, later xt
    float* buf2 = (float*)(ws + NH);         // h (in-place updated)
    float* buf3 = (float*)(ws + 2 * NH);     // agg
    float* deg  = (float*)(ws + 3 * NH);     // N floats

    hipMemsetAsync(buf1, 0, NH, stream);
    hipMemsetAsync(deg, 0, (size_t)N_NODES * sizeof(float), stream);

    const int eb = (N_EDGES * 32) / 256;     // 131072 blocks
    edge_init_kernel<<<eb, 256, 0, stream>>>(src, dst, etype, norm, global_id,
                                             emb_table, buf1, deg);
    proj_kernel<<<N_NODES, HID, 0, stream>>>(emb_table, global_id, spo, access,
                                             pre_access, buf1, deg, W_t, b_t, buf2);
    for (int l = 0; l < 2; ++l) {
        hipMemsetAsync(buf3, 0, NH, stream);
        for (int t = 0; t < 4; ++t) {
            xt_kernel<<<N_NODES, HID, 0, stream>>>(
                buf2, W_r + (size_t)(l * 4 + t) * HID * HID, buf1);
            edge_rgcn_kernel<<<eb, 256, 0, stream>>>(src, dst, etype, norm,
                                                     buf1, buf3, t);
        }
        update_kernel<<<(N_NODES * HID) / 256, 256, 0, stream>>>(
            buf2, buf3, b_r + l * HID, l == 0 ? 1 : 0);
    }
    predict_kernel<<<NB, 256, 0, stream>>>(buf2, pred_idx, Wb, bb, out);
}

// Round 2
// 1454.768 us; speedup vs baseline: 4.4841x; 4.4841x over previous
//
#include <hip/hip_runtime.h>
#include <hip/hip_bf16.h>

#define N_NODES 131072
#define N_EDGES 1048576
#define HID 128
#define NB 512
#define PPG 32
#define NKEYS (4 * N_NODES)          // (etype, dst) composite keys
#define NTILES (NKEYS / 256)         // 2048 scan tiles

// ===========================================================================
// CSR build: key = etype*N + dst.  rp starts as counts, becomes exclusive
// starts after scan, and scatter mutates starts into ends.
// Range for key k: [ k==0 ? 0 : rp[k-1],  rp[k] ).
// ===========================================================================
__global__ void count_kernel(const int* __restrict__ dst, const int* __restrict__ etype,
                             int* __restrict__ rp) {
    int e = blockIdx.x * blockDim.x + threadIdx.x;
    if (e >= N_EDGES) return;
    atomicAdd(rp + etype[e] * N_NODES + dst[e], 1);
}

__global__ void scan_tile_kernel(int* __restrict__ rp, int* __restrict__ tsum) {
    __shared__ int s[256];
    int g = blockIdx.x * 256 + threadIdx.x;
    int v = rp[g];
    s[threadIdx.x] = v;
    __syncthreads();
    for (int off = 1; off < 256; off <<= 1) {
        int tv = (threadIdx.x >= off) ? s[threadIdx.x - off] : 0;
        __syncthreads();
        s[threadIdx.x] += tv;
        __syncthreads();
    }
    rp[g] = s[threadIdx.x] - v;                    // exclusive within tile
    if (threadIdx.x == 255) tsum[blockIdx.x] = s[255];
}

__global__ void scan_tsum_kernel(int* __restrict__ tsum) {   // 1 block x 256
    __shared__ int s[256];
    int t = threadIdx.x;
    int loc[8]; int sum = 0;
#pragma unroll
    for (int i = 0; i < 8; ++i) { loc[i] = tsum[t * 8 + i]; sum += loc[i]; }
    s[t] = sum;
    __syncthreads();
    for (int off = 1; off < 256; off <<= 1) {
        int tv = (t >= off) ? s[t - off] : 0;
        __syncthreads();
        s[t] += tv;
        __syncthreads();
    }
    int run = s[t] - sum;                          // exclusive
#pragma unroll
    for (int i = 0; i < 8; ++i) { int v = loc[i]; tsum[t * 8 + i] = run; run += v; }
}

__global__ void scan_add_kernel(int* __restrict__ rp, const int* __restrict__ tsum) {
    int g = blockIdx.x * 256 + threadIdx.x;
    rp[g] += tsum[g >> 8];
}

__global__ void scatter_kernel(const int* __restrict__ src, const int* __restrict__ dst,
                               const int* __restrict__ etype, const float* __restrict__ norm,
                               int* __restrict__ rp, int* __restrict__ ssrc,
                               float* __restrict__ snorm) {
    int e = blockIdx.x * blockDim.x + threadIdx.x;
    if (e >= N_EDGES) return;
    int key = etype[e] * N_NODES + dst[e];
    int pos = atomicAdd(rp + key, 1);              // start -> end as we go
    ssrc[pos] = src[e];
    snorm[pos] = norm[e];
}

// ===========================================================================
// init aggregation over 'ne' (type 0) edges: agg0[dst] = sum norm*emb[gid[src]]
// wave per dst, 2 floats per lane.
// ===========================================================================
__global__ __launch_bounds__(256) void init_agg_kernel(
        const int* __restrict__ rp, const int* __restrict__ ssrc,
        const float* __restrict__ snorm, const int* __restrict__ global_id,
        const float* __restrict__ emb, float* __restrict__ agg0) {
    int wave = threadIdx.x >> 6, lane = threadIdx.x & 63;
    int d = blockIdx.x * 4 + wave;
    int rb = (d == 0) ? 0 : rp[d - 1];             // key = 0*N + d
    int re = rp[d];
    float ax = 0.f, ay = 0.f;
    for (int i = rb; i < re; ++i) {
        int s = ssrc[i];
        float nm = snorm[i];
        int gid = global_id[s];
        float2 v = ((const float2*)(emb + (size_t)gid * HID))[lane];
        ax += v.x * nm; ay += v.y * nm;
    }
    float2* o = (float2*)(agg0 + (size_t)d * HID);
    o[lane] = make_float2(ax, ay);
}

// ===========================================================================
// proj GEMM: h = concat(emb', spo, access, pre_access) @ W_t + b_t
// 128-node tile per block; At[136][132] (transposed, padded) + Ws[136][128] in LDS.
// Thread computes 8 rows x (4 + 4) cols (split halves to avoid bank conflicts).
// ===========================================================================
__global__ __launch_bounds__(256, 1) void proj_gemm_kernel(
        const float* __restrict__ emb, const int* __restrict__ global_id,
        const int* __restrict__ spo, const int* __restrict__ access,
        const int* __restrict__ pre_access, const float* __restrict__ agg0,
        const int* __restrict__ rp, const float* __restrict__ W_t,
        const float* __restrict__ b_t, float* __restrict__ h) {
    __shared__ float At[136][132];
    __shared__ float Ws[136][128];
    int tid = threadIdx.x;
    int base = blockIdx.x * 128;
    // W load: 133 real rows + 3 zero rows
    for (int i = tid; i < 4256; i += 256) ((float4*)Ws)[i] = ((const float4*)W_t)[i];
    for (int i = tid; i < 96; i += 256) ((float4*)Ws)[4256 + i] = make_float4(0, 0, 0, 0);
    // A tile (transposed): pair of threads per node
    {
        int n = tid >> 1, h2 = tid & 1;
        int node = base + n;
        int s0 = spo[node * 3 + 0], s2 = spo[node * 3 + 2];
        int rb = (node == 0) ? 0 : rp[node - 1];
        int re = rp[node];
        bool use_agg = ((s0 + s2) > 0) && (re > rb);
        const float* srcrow = use_agg ? (agg0 + (size_t)node * HID)
                                      : (emb + (size_t)global_id[node] * HID);
        srcrow += h2 * 64;
#pragma unroll
        for (int i = 0; i < 16; ++i) {
            float4 v = ((const float4*)srcrow)[i];
            int k = h2 * 64 + i * 4;
            At[k + 0][n] = v.x; At[k + 1][n] = v.y; At[k + 2][n] = v.z; At[k + 3][n] = v.w;
        }
    }
    if (tid < 128) {
        int node = base + tid;
        At[128][tid] = (float)spo[node * 3 + 0];
        At[129][tid] = (float)spo[node * 3 + 1];
        At[130][tid] = (float)spo[node * 3 + 2];
        At[131][tid] = (float)access[node];
        At[132][tid] = (float)pre_access[node];
        At[133][tid] = 0.f; At[134][tid] = 0.f; At[135][tid] = 0.f;
    }
    __syncthreads();
    int r0 = (tid >> 4) * 8, c0 = (tid & 15) * 4;
    float acc[8][8] = {};
#pragma unroll 2
    for (int k = 0; k < 136; ++k) {
        float a[8], w[8];
#pragma unroll
        for (int i = 0; i < 8; ++i) a[i] = At[k][r0 + i];
#pragma unroll
        for (int j = 0; j < 4; ++j) { w[j] = Ws[k][c0 + j]; w[4 + j] = Ws[k][64 + c0 + j]; }
#pragma unroll
        for (int i = 0; i < 8; ++i)
#pragma unroll
            for (int j = 0; j < 8; ++j) acc[i][j] += a[i] * w[j];
    }
    float b0[4], b1[4];
#pragma unroll
    for (int j = 0; j < 4; ++j) { b0[j] = b_t[c0 + j]; b1[j] = b_t[64 + c0 + j]; }
#pragma unroll
    for (int i = 0; i < 8; ++i) {
        float* row = h + (size_t)(base + r0 + i) * HID;
        float4 v0 = make_float4(acc[i][0] + b0[0], acc[i][1] + b0[1], acc[i][2] + b0[2], acc[i][3] + b0[3]);
        float4 v1 = make_float4(acc[i][4] + b1[0], acc[i][5] + b1[1], acc[i][6] + b1[2], acc[i][7] + b1[3]);
        ((float4*)(row + c0))[0] = v0;
        ((float4*)(row + 64 + c0))[0] = v1;
    }
}

// ===========================================================================
// xt GEMM: xt = h @ Wr  (K=128), same tiling as proj.
// ===========================================================================
__global__ __launch_bounds__(256, 1) void xt_gemm_kernel(
        const float* __restrict__ A, const float* __restrict__ W,
        float* __restrict__ C) {
    __shared__ float At[128][132];
    __shared__ float Ws[128][128];
    int tid = threadIdx.x;
    int base = blockIdx.x * 128;
    for (int i = tid; i < 4096; i += 256) ((float4*)Ws)[i] = ((const float4*)W)[i];
    {
        int n = tid >> 1, h2 = tid & 1;
        const float* srcrow = A + (size_t)(base + n) * HID + h2 * 64;
#pragma unroll
        for (int i = 0; i < 16; ++i) {
            float4 v = ((const float4*)srcrow)[i];
            int k = h2 * 64 + i * 4;
            At[k + 0][n] = v.x; At[k + 1][n] = v.y; At[k + 2][n] = v.z; At[k + 3][n] = v.w;
        }
    }
    __syncthreads();
    int r0 = (tid >> 4) * 8, c0 = (tid & 15) * 4;
    float acc[8][8] = {};
#pragma unroll 2
    for (int k = 0; k < 128; ++k) {
        float a[8], w[8];
#pragma unroll
        for (int i = 0; i < 8; ++i) a[i] = At[k][r0 + i];
#pragma unroll
        for (int j = 0; j < 4; ++j) { w[j] = Ws[k][c0 + j]; w[4 + j] = Ws[k][64 + c0 + j]; }
#pragma unroll
        for (int i = 0; i < 8; ++i)
#pragma unroll
            for (int j = 0; j < 8; ++j) acc[i][j] += a[i] * w[j];
    }
#pragma unroll
    for (int i = 0; i < 8; ++i) {
        float* row = C + (size_t)(base + r0 + i) * HID;
        ((float4*)(row + c0))[0]      = make_float4(acc[i][0], acc[i][1], acc[i][2], acc[i][3]);
        ((float4*)(row + 64 + c0))[0] = make_float4(acc[i][4], acc[i][5], acc[i][6], acc[i][7]);
    }
}

// ===========================================================================
// RGCN aggregation for one edge type.  Wave per dst node.
// t==0: write agg; t==1,2: accumulate; t==3: fuse bias+relu(+residual) -> h.
// ===========================================================================
__global__ __launch_bounds__(256) void aggregate_kernel(
        const int* __restrict__ rp, const int* __restrict__ ssrc,
        const float* __restrict__ snorm, const float* __restrict__ xt,
        float* __restrict__ agg, float* __restrict__ h,
        const float* __restrict__ b_r, int t, int residual) {
    int wave = threadIdx.x >> 6, lane = threadIdx.x & 63;
    int d = blockIdx.x * 4 + wave;
    int key = t * N_NODES + d;
    int rb = (key == 0) ? 0 : rp[key - 1];
    int re = rp[key];
    float ax = 0.f, ay = 0.f;
    for (int i = rb; i < re; ++i) {
        int s = ssrc[i];
        float nm = snorm[i];
        float2 v = ((const float2*)(xt + (size_t)s * HID))[lane];
        ax += v.x * nm; ay += v.y * nm;
    }
    float2* arow = (float2*)(agg + (size_t)d * HID);
    if (t == 0) {
        arow[lane] = make_float2(ax, ay);
    } else if (t < 3) {
        if (re > rb) {
            float2 p = arow[lane];
            arow[lane] = make_float2(p.x + ax, p.y + ay);
        }
    } else {
        float2 p = arow[lane];
        float vx = fmaxf(p.x + ax + b_r[lane * 2 + 0], 0.f);
        float vy = fmaxf(p.y + ay + b_r[lane * 2 + 1], 0.f);
        float2* hrow = (float2*)(h + (size_t)d * HID);
        if (residual) { float2 hp = hrow[lane]; vx += hp.x; vy += hp.y; }
        hrow[lane] = make_float2(vx, vy);
    }
}

// ===========================================================================
// predict (unchanged)
// ===========================================================================
__global__ void predict_kernel(const float* __restrict__ h, const int* __restrict__ pred_idx,
                               const float* __restrict__ Wb, const float* __restrict__ bbp,
                               float* __restrict__ out) {
    int b = blockIdx.x;
    int tid = threadIdx.x;
    __shared__ float hp[PPG * HID];
    __shared__ float pool[HID];
    __shared__ float vv[HID];
    __shared__ float sc[PPG];
    __shared__ float lse;
    for (int k = tid; k < PPG * HID; k += 256) {
        int p = k >> 7, j = k & 127;
        int node = pred_idx[b * PPG + p];
        hp[k] = h[(size_t)node * HID + j];
    }
    __syncthreads();
    if (tid < HID) {
        float s = 0.f;
        for (int p = 0; p < PPG; ++p) s += hp[p * HID + tid];
        pool[tid] = s * (1.0f / PPG);
    }
    __syncthreads();
    if (tid < HID) {
        float s = 0.f;
        for (int k = 0; k < HID; ++k) s += Wb[tid * HID + k] * pool[k];
        vv[tid] = s;
    }
    __syncthreads();
    if (tid < PPG) {
        float s = bbp[0];
        for (int j = 0; j < HID; ++j) s += hp[tid * HID + j] * vv[j];
        sc[tid] = s;
    }
    __syncthreads();
    if (tid == 0) {
        float m = -INFINITY;
        for (int p = 0; p < PPG; ++p) m = fmaxf(m, sc[p]);
        float se = 0.f;
        for (int p = 0; p < PPG; ++p) se += expf(sc[p] - m);
        lse = m + logf(se);
    }
    __syncthreads();
    if (tid < PPG) out[b * PPG + tid] = sc[tid] - lse;
}

extern "C" void kernel_launch(void* const* d_in, const int* in_sizes, int n_in,
                              void* d_out, int out_size, void* d_ws, size_t ws_size,
                              hipStream_t stream) {
    const float* emb_table  = (const float*)d_in[0];
    const float* W_t        = (const float*)d_in[1];
    const float* b_t        = (const float*)d_in[2];
    const float* W_r        = (const float*)d_in[3];
    const float* b_r        = (const float*)d_in[4];
    const float* Wb         = (const float*)d_in[5];
    const float* bb         = (const float*)d_in[6];
    const float* norm       = (const float*)d_in[7];
    const int*   global_id  = (const int*)d_in[8];
    const int*   spo        = (const int*)d_in[9];
    const int*   access     = (const int*)d_in[10];
    const int*   pre_access = (const int*)d_in[11];
    const int*   src        = (const int*)d_in[12];
    const int*   dst        = (const int*)d_in[13];
    const int*   etype      = (const int*)d_in[14];
    const int*   pred_idx   = (const int*)d_in[15];
    float* out = (float*)d_out;

    char* ws = (char*)d_ws;
    size_t NH = (size_t)N_NODES * HID * sizeof(float);   // 64 MiB
    float* h_buf  = (float*)(ws);
    float* xt_buf = (float*)(ws + NH);                   // also agg0 in init phase
    float* agg    = (float*)(ws + 2 * NH);
    int*   rp     = (int*)(ws + 3 * NH);                 // NKEYS ints
    int*   tsum   = (int*)(ws + 3 * NH + (size_t)NKEYS * 4);
    int*   ssrc   = (int*)(ws + 3 * NH + (size_t)NKEYS * 4 + 16384);
    float* snorm  = (float*)((char*)ssrc + (size_t)N_EDGES * 4);

    // ---- CSR build ----
    hipMemsetAsync(rp, 0, (size_t)NKEYS * 4, stream);
    count_kernel<<<N_EDGES / 256, 256, 0, stream>>>(dst, etype, rp);
    scan_tile_kernel<<<NTILES, 256, 0, stream>>>(rp, tsum);
    scan_tsum_kernel<<<1, 256, 0, stream>>>(tsum);
    scan_add_kernel<<<NTILES, 256, 0, stream>>>(rp, tsum);
    scatter_kernel<<<N_EDGES / 256, 256, 0, stream>>>(src, dst, etype, norm, rp, ssrc, snorm);

    // ---- init + input projection ----
    init_agg_kernel<<<N_NODES / 4, 256, 0, stream>>>(rp, ssrc, snorm, global_id,
                                                     emb_table, xt_buf);
    proj_gemm_kernel<<<N_NODES / 128, 256, 0, stream>>>(emb_table, global_id, spo, access,
                                                        pre_access, xt_buf, rp, W_t, b_t, h_buf);
    // ---- RGCN layers ----
    for (int l = 0; l < 2; ++l) {
        for (int t = 0; t < 4; ++t) {
            xt_gemm_kernel<<<N_NODES / 128, 256, 0, stream>>>(
                h_buf, W_r + (size_t)(l * 4 + t) * HID * HID, xt_buf);
            aggregate_kernel<<<N_NODES / 4, 256, 0, stream>>>(
                rp, ssrc, snorm, xt_buf, agg, h_buf, b_r + l * HID, t, l == 0 ? 1 : 0);
        }
    }
    predict_kernel<<<NB, 256, 0, stream>>>(h_buf, pred_idx, Wb, bb, out);
}

// Round 3
// 701.706 us; speedup vs baseline: 9.2963x; 2.0732x over previous
//
#include <hip/hip_runtime.h>
#include <hip/hip_bf16.h>

#define N_NODES 131072
#define N_EDGES 1048576
#define HID 128
#define NB 512
#define PPG 32
#define NKEYS (4 * N_NODES)
#define NTILES (NKEYS / 256)
#define KPROJ 160              // 133 real K, zero-padded
#define KLAY  512              // 4 types x 128

typedef short bf16x8 __attribute__((ext_vector_type(8)));
typedef float f32x4  __attribute__((ext_vector_type(4)));

__device__ __forceinline__ float bf2f(unsigned short u) {
    return __uint_as_float(((unsigned int)u) << 16);
}
__device__ __forceinline__ unsigned short f2bf(float x) {
    unsigned int u = __float_as_uint(x);
    unsigned int r = ((u >> 16) & 1u) + 0x7fffu;   // RNE
    return (unsigned short)((u + r) >> 16);
}
__device__ __forceinline__ unsigned int pack2(float a, float b) {
    return (unsigned int)f2bf(a) | ((unsigned int)f2bf(b) << 16);
}

// ===========================================================================
// CSR build: key = etype*N + dst
// ===========================================================================
__global__ void count_kernel(const int* __restrict__ dst, const int* __restrict__ etype,
                             int* __restrict__ rp) {
    int e = blockIdx.x * blockDim.x + threadIdx.x;
    if (e >= N_EDGES) return;
    atomicAdd(rp + etype[e] * N_NODES + dst[e], 1);
}

__global__ void scan_tile_kernel(int* __restrict__ rp, int* __restrict__ tsum) {
    __shared__ int s[256];
    int g = blockIdx.x * 256 + threadIdx.x;
    int v = rp[g];
    s[threadIdx.x] = v;
    __syncthreads();
    for (int off = 1; off < 256; off <<= 1) {
        int tv = (threadIdx.x >= off) ? s[threadIdx.x - off] : 0;
        __syncthreads();
        s[threadIdx.x] += tv;
        __syncthreads();
    }
    rp[g] = s[threadIdx.x] - v;
    if (threadIdx.x == 255) tsum[blockIdx.x] = s[255];
}

__global__ void scan_tsum_kernel(int* __restrict__ tsum) {
    __shared__ int s[256];
    int t = threadIdx.x;
    int loc[8]; int sum = 0;
#pragma unroll
    for (int i = 0; i < 8; ++i) { loc[i] = tsum[t * 8 + i]; sum += loc[i]; }
    s[t] = sum;
    __syncthreads();
    for (int off = 1; off < 256; off <<= 1) {
        int tv = (t >= off) ? s[t - off] : 0;
        __syncthreads();
        s[t] += tv;
        __syncthreads();
    }
    int run = s[t] - sum;
#pragma unroll
    for (int i = 0; i < 8; ++i) { int v = loc[i]; tsum[t * 8 + i] = run; run += v; }
}

__global__ void scan_add_kernel(int* __restrict__ rp, const int* __restrict__ tsum) {
    int g = blockIdx.x * 256 + threadIdx.x;
    rp[g] += tsum[g >> 8];
}

__global__ void scatter_kernel(const int* __restrict__ src, const int* __restrict__ dst,
                               const int* __restrict__ etype, const float* __restrict__ norm,
                               int* __restrict__ rp, int* __restrict__ ssrc,
                               float* __restrict__ snorm) {
    int e = blockIdx.x * blockDim.x + threadIdx.x;
    if (e >= N_EDGES) return;
    int key = etype[e] * N_NODES + dst[e];
    int pos = atomicAdd(rp + key, 1);
    ssrc[pos] = src[e];
    snorm[pos] = norm[e];
}

// ===========================================================================
// Weight pre-transpose to bf16 [outcol][k] layout.
// WTp[c][k] (k<133: W_t[k][c], else 0);  WTl[l][c][t*128+i] = W_r[l][t][i][c]
// ===========================================================================
__global__ void wtrans_kernel(const float* __restrict__ W_t, const float* __restrict__ W_r,
                              unsigned short* __restrict__ WTp, unsigned short* __restrict__ WTl) {
    int u = blockIdx.x * 256 + threadIdx.x;
    if (u < 2560) {                       // proj: 128 cols x 20 kgroups
        int c = u / 20, k0 = (u % 20) * 8;
#pragma unroll
        for (int j = 0; j < 8; ++j) {
            int k = k0 + j;
            float v = (k < 133) ? W_t[k * HID + c] : 0.f;
            WTp[c * KPROJ + k] = f2bf(v);
        }
    } else if (u < 2560 + 16384) {        // layers: 2 x 128 cols x 64 kgroups
        int v = u - 2560;
        int l = v / 8192; int rr = v % 8192;
        int c = rr / 64; int k0 = (rr % 64) * 8;
#pragma unroll
        for (int j = 0; j < 8; ++j) {
            int k = k0 + j; int t = k >> 7; int i = k & 127;
            float w = W_r[(((size_t)(l * 4 + t) * HID) + i) * HID + c];
            WTl[((size_t)l * HID + c) * KLAY + k] = f2bf(w);
        }
    }
}

// ===========================================================================
// prep: build A0[N][160] bf16 = concat(emb', feats, zeros).
// emb' = (is_ne && deg>0) ? sum norm*emb[gid[src]] over type-0 edges : emb[gid[n]]
// wave per node.
// ===========================================================================
__global__ __launch_bounds__(256) void prep_kernel(
        const int* __restrict__ rp, const int* __restrict__ ssrc,
        const float* __restrict__ snorm, const int* __restrict__ gid,
        const int* __restrict__ spo, const int* __restrict__ access,
        const int* __restrict__ pre, const float* __restrict__ emb,
        unsigned short* __restrict__ A0) {
    int wave = threadIdx.x >> 6, lane = threadIdx.x & 63;
    int n = blockIdx.x * 4 + wave;
    int s0 = spo[n * 3], s1 = spo[n * 3 + 1], s2 = spo[n * 3 + 2];
    int rb = n ? rp[n - 1] : 0, re = rp[n];
    float ax, ay;
    if ((s0 + s2) > 0 && re > rb) {
        ax = 0.f; ay = 0.f;
        for (int i = rb; i < re; ++i) {
            int s = ssrc[i]; float nm = snorm[i];
            float2 v = ((const float2*)(emb + (size_t)gid[s] * HID))[lane];
            ax += v.x * nm; ay += v.y * nm;
        }
    } else {
        float2 v = ((const float2*)(emb + (size_t)gid[n] * HID))[lane];
        ax = v.x; ay = v.y;
    }
    unsigned int* row = (unsigned int*)(A0 + (size_t)n * KPROJ);
    row[lane] = pack2(ax, ay);
    if (lane < 16) {
        int c0 = 128 + lane * 2;
        float f0 = 0.f, f1 = 0.f;
        if (c0 == 128)      { f0 = (float)s0;      f1 = (float)s1; }
        else if (c0 == 130) { f0 = (float)s2;      f1 = (float)access[n]; }
        else if (c0 == 132) { f0 = (float)pre[n];  f1 = 0.f; }
        row[64 + lane] = pack2(f0, f1);
    }
}

// ===========================================================================
// aggregation: Aagg[d][t*128 + j] = sum over type-t edges into d of norm*hb[src][j]
// wave per dst node, loops the 4 types.
// ===========================================================================
__global__ __launch_bounds__(256) void agg_kernel(
        const int* __restrict__ rp, const int* __restrict__ ssrc,
        const float* __restrict__ snorm, const unsigned short* __restrict__ hb,
        unsigned short* __restrict__ Aagg) {
    int wave = threadIdx.x >> 6, lane = threadIdx.x & 63;
    int d = blockIdx.x * 4 + wave;
    unsigned int* orow = (unsigned int*)(Aagg + (size_t)d * KLAY);
#pragma unroll
    for (int t = 0; t < 4; ++t) {
        int key = t * N_NODES + d;
        int rb = key ? rp[key - 1] : 0;
        int re = rp[key];
        float ax = 0.f, ay = 0.f;
        for (int i = rb; i < re; ++i) {
            int s = ssrc[i]; float nm = snorm[i];
            unsigned int v = ((const unsigned int*)(hb + (size_t)s * HID))[lane];
            ax += bf2f((unsigned short)(v & 0xffffu)) * nm;
            ay += bf2f((unsigned short)(v >> 16)) * nm;
        }
        orow[t * 64 + lane] = pack2(ax, ay);
    }
}

// ===========================================================================
// MFMA GEMM: C[128-tile][128] = A[N][K]_bf16 @ WT^T (+bias, mode epilogue)
// mode 0: out = acc+b            (proj)
// mode 1: out = relu(acc+b)+hb   (layer 0, residual)
// mode 2: out = relu(acc+b)      (layer 1)
// 256 thr / 4 waves, each wave a 64x64 quadrant; 16x16x32 bf16 MFMA.
// ===========================================================================
__global__ __launch_bounds__(256) void gemm_kernel(
        const unsigned short* __restrict__ A, int K,
        const unsigned short* __restrict__ WT, const float* __restrict__ bias,
        unsigned short* __restrict__ hb, int mode) {
    __shared__ unsigned short At[128][136];
    __shared__ unsigned short Bt[128][136];
    int tid = threadIdx.x;
    int base = blockIdx.x * 128;
    int wid = tid >> 6, lane = tid & 63;
    int wr = wid >> 1, wc = wid & 1;
    int lr = lane & 15, lk = (lane >> 4) * 8;
    f32x4 acc[4][4];
#pragma unroll
    for (int m = 0; m < 4; ++m)
#pragma unroll
        for (int n = 0; n < 4; ++n) { acc[m][n][0] = 0.f; acc[m][n][1] = 0.f; acc[m][n][2] = 0.f; acc[m][n][3] = 0.f; }
    int row2 = tid >> 1, half = tid & 1;
    for (int k0 = 0; k0 < K; k0 += 128) {
        int bk = K - k0; if (bk > 128) bk = 128;
        int hw = bk >> 1;                 // elems per half-row per thread
        int nld = bk >> 4;                // 16B loads per thread
        const unsigned short* ga = A  + (size_t)(base + row2) * K + k0 + half * hw;
        const unsigned short* gb = WT + (size_t)row2 * K + k0 + half * hw;
        __syncthreads();
        for (int i = 0; i < nld; ++i) {
            uint4 va = ((const uint4*)ga)[i];
            *((uint4*)&At[row2][half * hw + i * 8]) = va;
            uint4 vb = ((const uint4*)gb)[i];
            *((uint4*)&Bt[row2][half * hw + i * 8]) = vb;
        }
        __syncthreads();
        int ks = bk >> 5;
        for (int kk = 0; kk < ks; ++kk) {
            bf16x8 a[4], b[4];
#pragma unroll
            for (int m = 0; m < 4; ++m)
                a[m] = *(const bf16x8*)&At[wr * 64 + m * 16 + lr][kk * 32 + lk];
#pragma unroll
            for (int n = 0; n < 4; ++n)
                b[n] = *(const bf16x8*)&Bt[wc * 64 + n * 16 + lr][kk * 32 + lk];
#pragma unroll
            for (int m = 0; m < 4; ++m)
#pragma unroll
                for (int n = 0; n < 4; ++n)
                    acc[m][n] = __builtin_amdgcn_mfma_f32_16x16x32_bf16(a[m], b[n], acc[m][n], 0, 0, 0);
        }
    }
    float bcol[4];
#pragma unroll
    for (int n = 0; n < 4; ++n) bcol[n] = bias[wc * 64 + n * 16 + lr];
    int r0g = (lane >> 4) * 4;
#pragma unroll
    for (int m = 0; m < 4; ++m) {
        int row = base + wr * 64 + m * 16 + r0g;
#pragma unroll
        for (int n = 0; n < 4; ++n) {
            int col = wc * 64 + n * 16 + lr;
#pragma unroll
            for (int r = 0; r < 4; ++r) {
                float v = acc[m][n][r] + bcol[n];
                size_t idx = (size_t)(row + r) * HID + col;
                if (mode == 1)      v = fmaxf(v, 0.f) + bf2f(hb[idx]);
                else if (mode == 2) v = fmaxf(v, 0.f);
                hb[idx] = f2bf(v);
            }
        }
    }
}

// ===========================================================================
// predict (h in bf16)
// ===========================================================================
__global__ void predict_kernel(const unsigned short* __restrict__ hb,
                               const int* __restrict__ pred_idx,
                               const float* __restrict__ Wb, const float* __restrict__ bbp,
                               float* __restrict__ out) {
    int b = blockIdx.x;
    int tid = threadIdx.x;
    __shared__ float hp[PPG * HID];
    __shared__ float pool[HID];
    __shared__ float vv[HID];
    __shared__ float sc[PPG];
    __shared__ float lse;
    for (int k = tid; k < PPG * HID; k += 256) {
        int p = k >> 7, j = k & 127;
        int node = pred_idx[b * PPG + p];
        hp[k] = bf2f(hb[(size_t)node * HID + j]);
    }
    __syncthreads();
    if (tid < HID) {
        float s = 0.f;
        for (int p = 0; p < PPG; ++p) s += hp[p * HID + tid];
        pool[tid] = s * (1.0f / PPG);
    }
    __syncthreads();
    if (tid < HID) {
        float s = 0.f;
        for (int k = 0; k < HID; ++k) s += Wb[tid * HID + k] * pool[k];
        vv[tid] = s;
    }
    __syncthreads();
    if (tid < PPG) {
        float s = bbp[0];
        for (int j = 0; j < HID; ++j) s += hp[tid * HID + j] * vv[j];
        sc[tid] = s;
    }
    __syncthreads();
    if (tid == 0) {
        float m = -INFINITY;
        for (int p = 0; p < PPG; ++p) m = fmaxf(m, sc[p]);
        float se = 0.f;
        for (int p = 0; p < PPG; ++p) se += expf(sc[p] - m);
        lse = m + logf(se);
    }
    __syncthreads();
    if (tid < PPG) out[b * PPG + tid] = sc[tid] - lse;
}

extern "C" void kernel_launch(void* const* d_in, const int* in_sizes, int n_in,
                              void* d_out, int out_size, void* d_ws, size_t ws_size,
                              hipStream_t stream) {
    const float* emb_table  = (const float*)d_in[0];
    const float* W_t        = (const float*)d_in[1];
    const float* b_t        = (const float*)d_in[2];
    const float* W_r        = (const float*)d_in[3];
    const float* b_r        = (const float*)d_in[4];
    const float* Wb         = (const float*)d_in[5];
    const float* bb         = (const float*)d_in[6];
    const float* norm       = (const float*)d_in[7];
    const int*   global_id  = (const int*)d_in[8];
    const int*   spo        = (const int*)d_in[9];
    const int*   access     = (const int*)d_in[10];
    const int*   pre_access = (const int*)d_in[11];
    const int*   src        = (const int*)d_in[12];
    const int*   dst        = (const int*)d_in[13];
    const int*   etype      = (const int*)d_in[14];
    const int*   pred_idx   = (const int*)d_in[15];
    float* out = (float*)d_out;

    char* ws = (char*)d_ws;
    size_t off = 0;
    unsigned short* hb   = (unsigned short*)(ws + off); off += (size_t)N_NODES * HID * 2;      // 32 MiB
    unsigned short* Abuf = (unsigned short*)(ws + off); off += (size_t)N_NODES * KLAY * 2;     // 128 MiB (A0 lives here too)
    int*   rp    = (int*)(ws + off);   off += (size_t)NKEYS * 4;                                // 2 MiB
    int*   tsum  = (int*)(ws + off);   off += (size_t)NTILES * 4;
    int*   ssrc  = (int*)(ws + off);   off += (size_t)N_EDGES * 4;                              // 4 MiB
    float* snorm = (float*)(ws + off); off += (size_t)N_EDGES * 4;                              // 4 MiB
    unsigned short* WTp = (unsigned short*)(ws + off); off += (size_t)HID * KPROJ * 2;
    unsigned short* WTl = (unsigned short*)(ws + off); off += (size_t)2 * HID * KLAY * 2;
    unsigned short* A0 = Abuf;   // [N][KPROJ], consumed before Aagg is written

    // ---- CSR build ----
    hipMemsetAsync(rp, 0, (size_t)NKEYS * 4, stream);
    count_kernel<<<N_EDGES / 256, 256, 0, stream>>>(dst, etype, rp);
    scan_tile_kernel<<<NTILES, 256, 0, stream>>>(rp, tsum);
    scan_tsum_kernel<<<1, 256, 0, stream>>>(tsum);
    scan_add_kernel<<<NTILES, 256, 0, stream>>>(rp, tsum);
    scatter_kernel<<<N_EDGES / 256, 256, 0, stream>>>(src, dst, etype, norm, rp, ssrc, snorm);

    // ---- weights to bf16 transposed ----
    wtrans_kernel<<<74, 256, 0, stream>>>(W_t, W_r, WTp, WTl);

    // ---- init aggregation + A0 build, then proj GEMM -> hb ----
    prep_kernel<<<N_NODES / 4, 256, 0, stream>>>(rp, ssrc, snorm, global_id, spo,
                                                 access, pre_access, emb_table, A0);
    gemm_kernel<<<N_NODES / 128, 256, 0, stream>>>(A0, KPROJ, WTp, b_t, hb, 0);

    // ---- RGCN layers: aggregate-then-transform ----
    agg_kernel<<<N_NODES / 4, 256, 0, stream>>>(rp, ssrc, snorm, hb, Abuf);
    gemm_kernel<<<N_NODES / 128, 256, 0, stream>>>(Abuf, KLAY, WTl, b_r, hb, 1);
    agg_kernel<<<N_NODES / 4, 256, 0, stream>>>(rp, ssrc, snorm, hb, Abuf);
    gemm_kernel<<<N_NODES / 128, 256, 0, stream>>>(Abuf, KLAY, WTl + (size_t)HID * KLAY,
                                                   b_r + HID, hb, 2);

    predict_kernel<<<NB, 256, 0, stream>>>(hb, pred_idx, Wb, bb, out);
}